// Round 13
// baseline (783.688 us; speedup 1.0000x reference)
//
#include <hip/hip_runtime.h>

#define DEV __device__ __forceinline__

static const int NN = 100000;
static const int EE = 1000000;
static const int ECAP = 1024;   // LDS-staged edges per block (32 nodes, avg ~320)

typedef unsigned int uv4 __attribute__((ext_vector_type(4)));

DEV float bf2f(unsigned int h) {
    unsigned int u = h << 16;
    float f;
    __builtin_memcpy(&f, &u, 4);
    return f;
}
DEV unsigned short f2bf(float f) {  // round-to-nearest-even
    unsigned int u;
    __builtin_memcpy(&u, &f, 4);
    u = u + 0x7FFFu + ((u >> 16) & 1u);
    return (unsigned short)(u >> 16);
}
DEV unsigned int pk2(float a, float b) {
    return (unsigned int)f2bf(a) | ((unsigned int)f2bf(b) << 16);
}
DEV void unpack8(uint4 u, float* v) {
    v[0] = bf2f(u.x & 0xffffu); v[1] = bf2f(u.x >> 16);
    v[2] = bf2f(u.y & 0xffffu); v[3] = bf2f(u.y >> 16);
    v[4] = bf2f(u.z & 0xffffu); v[5] = bf2f(u.z >> 16);
    v[6] = bf2f(u.w & 0xffffu); v[7] = bf2f(u.w >> 16);
}

// ---------------- CSR build (dual-graph via blockIdx.y) ----------------
__global__ __launch_bounds__(256) void k_count_dual(const int* __restrict__ d0, const int* __restrict__ d1,
                                                    int* __restrict__ c0, int* __restrict__ c1,
                                                    int* __restrict__ p0, int* __restrict__ p1, int e) {
    int g = blockIdx.y;
    const int* dst = g ? d1 : d0;
    int* cnt = g ? c1 : c0;
    int* pos = g ? p1 : p0;
    int i = blockIdx.x * blockDim.x + threadIdx.x;
    if (i < e) pos[i] = atomicAdd(&cnt[dst[i]], 1);
}
__global__ __launch_bounds__(256) void k_scan_partial_dual(const int* __restrict__ c0, const int* __restrict__ c1,
                                                           int* __restrict__ p0, int* __restrict__ p1,
                                                           float* __restrict__ v0, float* __restrict__ v1, int n) {
    int g = blockIdx.y;
    const int* cnt = g ? c1 : c0;
    int* partial = g ? p1 : p0;
    float* dinv = g ? v1 : v0;
    __shared__ int lds[256];
    int base = blockIdx.x * 1024;
    int t = threadIdx.x;
    int s = 0;
#pragma unroll
    for (int i = 0; i < 4; i++) {
        int idx = base + t * 4 + i;
        int c = (idx < n) ? cnt[idx] : 0;
        if (idx < n) dinv[idx] = rsqrtf((float)c + 1.0f);
        s += c;
    }
    lds[t] = s;
    __syncthreads();
    for (int off = 128; off > 0; off >>= 1) {
        if (t < off) lds[t] += lds[t + off];
        __syncthreads();
    }
    if (t == 0) partial[blockIdx.x] = lds[0];
}
// scan_write with INLINE top-level scan of partials
__global__ __launch_bounds__(256) void k_scan_write_dual(const int* __restrict__ c0, const int* __restrict__ c1,
                                                         const int* __restrict__ p0, const int* __restrict__ p1,
                                                         int* __restrict__ r0, int* __restrict__ r1,
                                                         int n, int total, int B) {
    int g = blockIdx.y;
    const int* cnt = g ? c1 : c0;
    const int* partial = g ? p1 : p0;
    int* rowptr = g ? r1 : r0;
    __shared__ int val[256];
    __shared__ int top[256];
    __shared__ int lds[256];
    __shared__ int base_s;
    int t = threadIdx.x;
    int pv = (t < B) ? partial[t] : 0;
    val[t] = pv;
    top[t] = pv;
    __syncthreads();
    for (int off = 1; off < 256; off <<= 1) {
        int x = (t >= off) ? top[t - off] : 0;
        __syncthreads();
        top[t] += x;
        __syncthreads();
    }
    if (t == 0) base_s = top[blockIdx.x] - val[blockIdx.x];
    __syncthreads();
    int base = blockIdx.x * 1024;
    int v[4];
    int s = 0;
#pragma unroll
    for (int i = 0; i < 4; i++) {
        int idx = base + t * 4 + i;
        v[i] = (idx < n) ? cnt[idx] : 0;
        s += v[i];
    }
    lds[t] = s;
    __syncthreads();
    int mine = s;
    for (int off = 1; off < 256; off <<= 1) {
        int x = (t >= off) ? lds[t - off] : 0;
        __syncthreads();
        lds[t] += x;
        __syncthreads();
    }
    int run = lds[t] - mine + base_s;
#pragma unroll
    for (int i = 0; i < 4; i++) {
        int idx = base + t * 4 + i;
        if (idx < n) rowptr[idx] = run;
        run += v[i];
    }
    if (blockIdx.x == 0 && t == 0) rowptr[n] = total;
}

// ---------------- merged fill + encoder (independent work, one dispatch) ----------------
__global__ __launch_bounds__(256, 4) void k_fillenc_dual(
    const int* __restrict__ s0, const int* __restrict__ s1,
    const int* __restrict__ q0, const int* __restrict__ q1,
    const int* __restrict__ r0, const int* __restrict__ r1,
    int* __restrict__ col0, int* __restrict__ col1, int e,
    const float* __restrict__ x0, const float* __restrict__ x1,
    const float* __restrict__ w1a, const float* __restrict__ w1b,
    const float* __restrict__ b1a, const float* __restrict__ b1b,
    const float* __restrict__ w2a, const float* __restrict__ w2b,
    const float* __restrict__ b2a, const float* __restrict__ b2b,
    const float* __restrict__ v0, const float* __restrict__ v1,
    unsigned short* __restrict__ y0, unsigned short* __restrict__ y1,
    int n, int nbe, int nbr) {
    int bx = blockIdx.x;
    int t = threadIdx.x;
    if (bx < 2 * nbe) {
        // ---- fill path (plain store: let L2 write-allocate merge the 4B scatters) ----
        int g = (bx >= nbe) ? 1 : 0;
        const int* src = g ? s1 : s0;
        const int* dstv = src + e;
        const int* pos = g ? q1 : q0;
        const int* rowptr = g ? r1 : r0;
        int* col = g ? col1 : col0;
        int i = (bx - g * nbe) * 256 + t;
        if (i >= e) return;
        int s = src[i], d = dstv[i];
        col[rowptr[d] + pos[i]] = s;
        return;
    }
    // ---- enc path ----
    int bx2 = bx - 2 * nbe;
    int g = (bx2 >= nbr) ? 1 : 0;
    const float* x = g ? x1 : x0;
    const float* w1 = g ? w1b : w1a;
    const float* b1 = g ? b1b : b1a;
    const float* w2 = g ? w2b : w2a;
    const float* b2 = g ? b2b : b2a;
    const float* dinv = g ? v1 : v0;
    unsigned short* out = g ? y1 : y0;
    int r = (bx2 - g * nbr) * 256 + t;
    if (r >= n) return;
    float4 xv = reinterpret_cast<const float4*>(x)[r];
    float xk[4] = {xv.x, xv.y, xv.z, xv.w};
    float d = dinv[r];
    uint4* o = reinterpret_cast<uint4*>(out + (size_t)r * 64);
#pragma unroll 1
    for (int oc = 0; oc < 4; oc++) {
        float h2[16];
#pragma unroll
        for (int j = 0; j < 16; j++) h2[j] = b2[oc * 16 + j];
#pragma unroll 1
        for (int c = 0; c < 8; c++) {
            float h[8];
#pragma unroll
            for (int i = 0; i < 8; i++) h[i] = b1[c * 8 + i];
#pragma unroll
            for (int k = 0; k < 4; k++) {
#pragma unroll
                for (int i = 0; i < 8; i++) h[i] = fmaf(xk[k], w1[k * 64 + c * 8 + i], h[i]);
            }
#pragma unroll
            for (int i = 0; i < 8; i++) h[i] = fmaxf(h[i], 0.0f);
#pragma unroll
            for (int i = 0; i < 8; i++) {
                const float* wr = w2 + (c * 8 + i) * 64 + oc * 16;
#pragma unroll
                for (int j = 0; j < 16; j++) h2[j] = fmaf(h[i], wr[j], h2[j]);
            }
        }
        uint4 u0, u1;
        u0.x = pk2(h2[0] * d, h2[1] * d);   u0.y = pk2(h2[2] * d, h2[3] * d);
        u0.z = pk2(h2[4] * d, h2[5] * d);   u0.w = pk2(h2[6] * d, h2[7] * d);
        u1.x = pk2(h2[8] * d, h2[9] * d);   u1.y = pk2(h2[10] * d, h2[11] * d);
        u1.z = pk2(h2[12] * d, h2[13] * d); u1.w = pk2(h2[14] * d, h2[15] * d);
        o[oc * 2 + 0] = u0;
        o[oc * 2 + 1] = u1;
    }
}

// ---------------- fused GCN layer (pre-scaled input h' = h*dinv), layers 1-2 ----------------
DEV void add_edge_v(float* acc, uint4 u) {
    float v[8];
    unpack8(u, v);
#pragma unroll
    for (int i = 0; i < 8; i++) acc[i] += v[i];
}
// gather helper: acc = self + sum of staged-edge rows (8-wide epochs)
DEV void gather_rows(const unsigned short* __restrict__ x, const int* __restrict__ eds,
                     const int* __restrict__ col, int ebase, int e, int e1, int cap,
                     int fbase, float* acc) {
    if (e1 <= cap) {
        for (; e + 8 <= e1; e += 8) {
            int s0 = eds[e + 0], s1 = eds[e + 1], s2 = eds[e + 2], s3 = eds[e + 3];
            int s4 = eds[e + 4], s5 = eds[e + 5], s6 = eds[e + 6], s7 = eds[e + 7];
            uint4 u0 = *reinterpret_cast<const uint4*>(x + (size_t)s0 * 64 + fbase);
            uint4 u1 = *reinterpret_cast<const uint4*>(x + (size_t)s1 * 64 + fbase);
            uint4 u2 = *reinterpret_cast<const uint4*>(x + (size_t)s2 * 64 + fbase);
            uint4 u3 = *reinterpret_cast<const uint4*>(x + (size_t)s3 * 64 + fbase);
            uint4 u4 = *reinterpret_cast<const uint4*>(x + (size_t)s4 * 64 + fbase);
            uint4 u5 = *reinterpret_cast<const uint4*>(x + (size_t)s5 * 64 + fbase);
            uint4 u6 = *reinterpret_cast<const uint4*>(x + (size_t)s6 * 64 + fbase);
            uint4 u7 = *reinterpret_cast<const uint4*>(x + (size_t)s7 * 64 + fbase);
            add_edge_v(acc, u0); add_edge_v(acc, u1); add_edge_v(acc, u2); add_edge_v(acc, u3);
            add_edge_v(acc, u4); add_edge_v(acc, u5); add_edge_v(acc, u6); add_edge_v(acc, u7);
        }
        if (e + 4 <= e1) {
            int s0 = eds[e + 0], s1 = eds[e + 1], s2 = eds[e + 2], s3 = eds[e + 3];
            uint4 u0 = *reinterpret_cast<const uint4*>(x + (size_t)s0 * 64 + fbase);
            uint4 u1 = *reinterpret_cast<const uint4*>(x + (size_t)s1 * 64 + fbase);
            uint4 u2 = *reinterpret_cast<const uint4*>(x + (size_t)s2 * 64 + fbase);
            uint4 u3 = *reinterpret_cast<const uint4*>(x + (size_t)s3 * 64 + fbase);
            add_edge_v(acc, u0); add_edge_v(acc, u1); add_edge_v(acc, u2); add_edge_v(acc, u3);
            e += 4;
        }
        if (e + 2 <= e1) {
            int s0 = eds[e + 0], s1 = eds[e + 1];
            uint4 u0 = *reinterpret_cast<const uint4*>(x + (size_t)s0 * 64 + fbase);
            uint4 u1 = *reinterpret_cast<const uint4*>(x + (size_t)s1 * 64 + fbase);
            add_edge_v(acc, u0); add_edge_v(acc, u1);
            e += 2;
        }
        if (e < e1) {
            int s0 = eds[e];
            uint4 u0 = *reinterpret_cast<const uint4*>(x + (size_t)s0 * 64 + fbase);
            add_edge_v(acc, u0);
        }
    } else {
        for (; e < e1; e++) {
            int s0 = __builtin_nontemporal_load(col + ebase + e);
            uint4 u0 = *reinterpret_cast<const uint4*>(x + (size_t)s0 * 64 + fbase);
            add_edge_v(acc, u0);
        }
    }
}
__global__ __launch_bounds__(256) void k_conv_dual(const unsigned short* __restrict__ x0,
                                                   const unsigned short* __restrict__ x1,
                                                   const int* __restrict__ col0, const int* __restrict__ col1,
                                                   const int* __restrict__ r0, const int* __restrict__ r1,
                                                   const float* __restrict__ v0, const float* __restrict__ v1,
                                                   const float* __restrict__ w0, const float* __restrict__ w1,
                                                   const float* __restrict__ b0, const float* __restrict__ b1,
                                                   unsigned short* __restrict__ y0, unsigned short* __restrict__ y1,
                                                   int nblk) {
    int bx = blockIdx.x;
    int xcd = bx & 7;
    int g = xcd >> 2;
    int lin = (bx >> 3) * 4 + (xcd & 3);
    if (lin >= nblk) return;
    const unsigned short* x = g ? x1 : x0;
    const int* col = g ? col1 : col0;
    const int* rowptr = g ? r1 : r0;
    const float* dinv = g ? v1 : v0;
    const float* w = g ? w1 : w0;
    const float* b = g ? b1 : b0;
    unsigned short* y = g ? y1 : y0;

    __shared__ int eds[ECAP];
    __shared__ float agg[32][68];

    int t = threadIdx.x;
    int cl = t >> 3;
    int ln = t & 7;
    int node = lin * 32 + cl;
    int fbase = ln * 8;

    int nbase = lin * 32;
    int ebase = rowptr[nbase];
    int L = rowptr[nbase + 32] - ebase;
    int Ls = (L < ECAP) ? L : ECAP;
    for (int i = t; i < Ls; i += 256) {
        eds[i] = __builtin_nontemporal_load(col + ebase + i);
    }

    float acc[8];
    float d = dinv[node];
    {
        uint4 su = *reinterpret_cast<const uint4*>(x + (size_t)node * 64 + fbase);
        float sv[8];
        unpack8(su, sv);
#pragma unroll
        for (int i = 0; i < 8; i++) acc[i] = sv[i];
    }
    int e = rowptr[node] - ebase, e1 = rowptr[node + 1] - ebase;
    __syncthreads();
    gather_rows(x, eds, col, ebase, e, e1, ECAP, fbase, acc);
#pragma unroll
    for (int i = 0; i < 8; i += 4) {
        *reinterpret_cast<float4*>(&agg[cl][fbase + i]) =
            make_float4(acc[i] * d, acc[i + 1] * d, acc[i + 2] * d, acc[i + 3] * d);
    }
    __syncthreads();

    float out[8];
#pragma unroll
    for (int i = 0; i < 8; i++) out[i] = b[fbase + i];
#pragma unroll 4
    for (int k4 = 0; k4 < 16; k4++) {
        float4 av = *reinterpret_cast<const float4*>(&agg[cl][k4 * 4]);
        float a[4] = {av.x, av.y, av.z, av.w};
#pragma unroll
        for (int kk = 0; kk < 4; kk++) {
            const float4* wr = reinterpret_cast<const float4*>(w + (k4 * 4 + kk) * 64 + fbase);
            float4 wv0 = wr[0], wv1 = wr[1];
            out[0] = fmaf(a[kk], wv0.x, out[0]);
            out[1] = fmaf(a[kk], wv0.y, out[1]);
            out[2] = fmaf(a[kk], wv0.z, out[2]);
            out[3] = fmaf(a[kk], wv0.w, out[3]);
            out[4] = fmaf(a[kk], wv1.x, out[4]);
            out[5] = fmaf(a[kk], wv1.y, out[5]);
            out[6] = fmaf(a[kk], wv1.z, out[6]);
            out[7] = fmaf(a[kk], wv1.w, out[7]);
        }
    }
    uint4 ou;
    float r[8];
#pragma unroll
    for (int i = 0; i < 8; i++) r[i] = fmaxf(out[i], 0.0f) * d;  // pre-scale for next conv
    ou.x = pk2(r[0], r[1]); ou.y = pk2(r[2], r[3]); ou.z = pk2(r[4], r[5]); ou.w = pk2(r[6], r[7]);
    *reinterpret_cast<uint4*>(y + (size_t)node * 64 + fbase) = ou;
}

// ---------------- fused conv layer 3 + fusion-MLP + heads ----------------
// Each block owns 32 nodes in BOTH graphs: gathers both, conv phase-2 both (yf/ys in
// LDS), then h1 = relu([yf|ys]w1+b1), h2 = h1 w2 + b2, heads -> f32 out. P never hits HBM.
__global__ __launch_bounds__(256) void k_conv3_tail(
    const unsigned short* __restrict__ x0, const unsigned short* __restrict__ x1,
    const int* __restrict__ col0, const int* __restrict__ col1,
    const int* __restrict__ r0, const int* __restrict__ r1,
    const float* __restrict__ v0, const float* __restrict__ v1,
    const float* __restrict__ wf, const float* __restrict__ wsd,
    const float* __restrict__ bf, const float* __restrict__ bs,
    const float* __restrict__ w1, const float* __restrict__ b1,
    const float* __restrict__ w2, const float* __restrict__ b2,
    const float* __restrict__ ow, const float* __restrict__ ob,
    const float* __restrict__ cw, const float* __restrict__ cb,
    float* __restrict__ out, int n) {
    __shared__ int eds0[ECAP];
    __shared__ int eds1[ECAP];
    __shared__ float aggf[32][68];
    __shared__ float aggs[32][68];
    __shared__ float yf[32][68];
    __shared__ float ys[32][68];

    int t = threadIdx.x;
    int cl = t >> 3;
    int ln = t & 7;
    int lin = blockIdx.x;
    int node = lin * 32 + cl;
    int fbase = ln * 8;
    int nbase = lin * 32;

    int eb0 = r0[nbase];
    int L0 = r0[nbase + 32] - eb0;
    int Ls0 = (L0 < ECAP) ? L0 : ECAP;
    for (int i = t; i < Ls0; i += 256) eds0[i] = __builtin_nontemporal_load(col0 + eb0 + i);
    int eb1 = r1[nbase];
    int L1 = r1[nbase + 32] - eb1;
    int Ls1 = (L1 < ECAP) ? L1 : ECAP;
    for (int i = t; i < Ls1; i += 256) eds1[i] = __builtin_nontemporal_load(col1 + eb1 + i);

    float d0v = v0[node];
    float d1v = v1[node];
    float acc[8];
    // graph 0 self
    {
        uint4 su = *reinterpret_cast<const uint4*>(x0 + (size_t)node * 64 + fbase);
        float sv[8];
        unpack8(su, sv);
#pragma unroll
        for (int i = 0; i < 8; i++) acc[i] = sv[i];
    }
    int e0 = r0[node] - eb0, e0e = r0[node + 1] - eb0;
    int e1 = r1[node] - eb1, e1e = r1[node + 1] - eb1;
    __syncthreads();
    gather_rows(x0, eds0, col0, eb0, e0, e0e, ECAP, fbase, acc);
#pragma unroll
    for (int i = 0; i < 8; i += 4) {
        *reinterpret_cast<float4*>(&aggf[cl][fbase + i]) =
            make_float4(acc[i] * d0v, acc[i + 1] * d0v, acc[i + 2] * d0v, acc[i + 3] * d0v);
    }
    // graph 1
    {
        uint4 su = *reinterpret_cast<const uint4*>(x1 + (size_t)node * 64 + fbase);
        float sv[8];
        unpack8(su, sv);
#pragma unroll
        for (int i = 0; i < 8; i++) acc[i] = sv[i];
    }
    gather_rows(x1, eds1, col1, eb1, e1, e1e, ECAP, fbase, acc);
#pragma unroll
    for (int i = 0; i < 8; i += 4) {
        *reinterpret_cast<float4*>(&aggs[cl][fbase + i]) =
            make_float4(acc[i] * d1v, acc[i + 1] * d1v, acc[i + 2] * d1v, acc[i + 3] * d1v);
    }
    __syncthreads();

    // phase B: yf = relu(aggf Wf + bf), ys = relu(aggs Ws + bs)
    {
        float of[8], os[8];
#pragma unroll
        for (int i = 0; i < 8; i++) { of[i] = bf[fbase + i]; os[i] = bs[fbase + i]; }
#pragma unroll 4
        for (int k4 = 0; k4 < 16; k4++) {
            float4 af = *reinterpret_cast<const float4*>(&aggf[cl][k4 * 4]);
            float4 as = *reinterpret_cast<const float4*>(&aggs[cl][k4 * 4]);
            float fa[4] = {af.x, af.y, af.z, af.w};
            float sa[4] = {as.x, as.y, as.z, as.w};
#pragma unroll
            for (int kk = 0; kk < 4; kk++) {
                const float4* wrf = reinterpret_cast<const float4*>(wf + (k4 * 4 + kk) * 64 + fbase);
                const float4* wrs = reinterpret_cast<const float4*>(wsd + (k4 * 4 + kk) * 64 + fbase);
                float4 f0 = wrf[0], f1 = wrf[1];
                float4 s0 = wrs[0], s1 = wrs[1];
                of[0] = fmaf(fa[kk], f0.x, of[0]); of[1] = fmaf(fa[kk], f0.y, of[1]);
                of[2] = fmaf(fa[kk], f0.z, of[2]); of[3] = fmaf(fa[kk], f0.w, of[3]);
                of[4] = fmaf(fa[kk], f1.x, of[4]); of[5] = fmaf(fa[kk], f1.y, of[5]);
                of[6] = fmaf(fa[kk], f1.z, of[6]); of[7] = fmaf(fa[kk], f1.w, of[7]);
                os[0] = fmaf(sa[kk], s0.x, os[0]); os[1] = fmaf(sa[kk], s0.y, os[1]);
                os[2] = fmaf(sa[kk], s0.z, os[2]); os[3] = fmaf(sa[kk], s0.w, os[3]);
                os[4] = fmaf(sa[kk], s1.x, os[4]); os[5] = fmaf(sa[kk], s1.y, os[5]);
                os[6] = fmaf(sa[kk], s1.z, os[6]); os[7] = fmaf(sa[kk], s1.w, os[7]);
            }
        }
#pragma unroll
        for (int i = 0; i < 8; i++) {
            yf[cl][fbase + i] = fmaxf(of[i], 0.0f);
            ys[cl][fbase + i] = fmaxf(os[i], 0.0f);
        }
    }
    __syncthreads();

    // phase C: h1 = relu([yf|ys] w1 + b1)  -> store into aggf (dead)
    {
        float h[8];
#pragma unroll
        for (int i = 0; i < 8; i++) h[i] = b1[fbase + i];
#pragma unroll 4
        for (int k = 0; k < 64; k++) {
            float a = yf[cl][k];
            const float* wr = w1 + k * 64 + fbase;
#pragma unroll
            for (int i = 0; i < 8; i++) h[i] = fmaf(a, wr[i], h[i]);
        }
#pragma unroll 4
        for (int k = 0; k < 64; k++) {
            float a = ys[cl][k];
            const float* wr = w1 + (64 + k) * 64 + fbase;
#pragma unroll
            for (int i = 0; i < 8; i++) h[i] = fmaf(a, wr[i], h[i]);
        }
#pragma unroll
        for (int i = 0; i < 8; i++) aggf[cl][fbase + i] = fmaxf(h[i], 0.0f);
    }
    __syncthreads();

    // phase D: h2 = h1 w2 + b2 -> store into aggs (dead)
    {
        float h[8];
#pragma unroll
        for (int i = 0; i < 8; i++) h[i] = b2[fbase + i];
#pragma unroll 4
        for (int k = 0; k < 64; k++) {
            float a = aggf[cl][k];
            const float* wr = w2 + k * 64 + fbase;
#pragma unroll
            for (int i = 0; i < 8; i++) h[i] = fmaf(a, wr[i], h[i]);
        }
#pragma unroll
        for (int i = 0; i < 8; i++) aggs[cl][fbase + i] = h[i];
    }
    __syncthreads();

    // heads: nf[32] (lane ln computes cols ln*4..ln*4+4), nt[2] (lane 0)
    {
        float nf[4];
#pragma unroll
        for (int j = 0; j < 4; j++) nf[j] = ob[ln * 4 + j];
#pragma unroll 4
        for (int k = 0; k < 64; k++) {
            float a = aggs[cl][k];
            const float* wr = ow + k * 32 + ln * 4;
#pragma unroll
            for (int j = 0; j < 4; j++) nf[j] = fmaf(a, wr[j], nf[j]);
        }
        *reinterpret_cast<float4*>(out + (size_t)node * 32 + ln * 4) =
            make_float4(nf[0], nf[1], nf[2], nf[3]);
        if (ln == 0) {
            float nt0 = cb[0], nt1 = cb[1];
#pragma unroll 4
            for (int k = 0; k < 64; k++) {
                float a = aggs[cl][k];
                nt0 = fmaf(a, cw[k * 2 + 0], nt0);
                nt1 = fmaf(a, cw[k * 2 + 1], nt1);
            }
            reinterpret_cast<float2*>(out + (size_t)NN * 32)[node] = make_float2(nt0, nt1);
        }
    }
}

extern "C" void kernel_launch(void* const* d_in, const int* in_sizes, int n_in,
                              void* d_out, int out_size, void* d_ws, size_t ws_size,
                              hipStream_t stream) {
    const int N = NN, E = EE;
    const float* front_x = (const float*)d_in[0];
    const float* side_x = (const float*)d_in[1];
    const int* fei = (const int*)d_in[2];
    const int* sei = (const int*)d_in[3];
    const float* fe_enc_w1 = (const float*)d_in[4];
    const float* fe_enc_b1 = (const float*)d_in[5];
    const float* fe_enc_w2 = (const float*)d_in[6];
    const float* fe_enc_b2 = (const float*)d_in[7];
    const float* fe_conv_w = (const float*)d_in[8];
    const float* fe_conv_b = (const float*)d_in[9];
    const float* se_enc_w1 = (const float*)d_in[10];
    const float* se_enc_b1 = (const float*)d_in[11];
    const float* se_enc_w2 = (const float*)d_in[12];
    const float* se_enc_b2 = (const float*)d_in[13];
    const float* se_conv_w = (const float*)d_in[14];
    const float* se_conv_b = (const float*)d_in[15];
    const float* fus_w1 = (const float*)d_in[16];
    const float* fus_b1 = (const float*)d_in[17];
    const float* fus_w2 = (const float*)d_in[18];
    const float* fus_b2 = (const float*)d_in[19];
    const float* out_w = (const float*)d_in[20];
    const float* out_b = (const float*)d_in[21];
    const float* cls_w = (const float*)d_in[22];
    const float* cls_b = (const float*)d_in[23];

    // workspace carve (256B aligned)
    char* ws = (char*)d_ws;
    size_t off = 0;
    auto take = [&](size_t bytes) -> char* {
        char* p = ws + off;
        off = (off + bytes + 255) & ~(size_t)255;
        return p;
    };
    int* zb = (int*)take((size_t)2 * N * 4);  // cnt0,cnt1 (zeroed)
    int* cnt0 = zb;
    int* cnt1 = zb + N;
    int* pos0 = (int*)take((size_t)E * 4);
    int* pos1 = (int*)take((size_t)E * 4);
    int* rp0 = (int*)take((size_t)(N + 1) * 4);
    int* rp1 = (int*)take((size_t)(N + 1) * 4);
    float* dv0 = (float*)take((size_t)N * 4);
    float* dv1 = (float*)take((size_t)N * 4);
    int* part0 = (int*)take(256 * 4);
    int* part1 = (int*)take(256 * 4);
    int* col0 = (int*)take((size_t)E * 4);
    int* col1 = (int*)take((size_t)E * 4);
    unsigned short* P0 = (unsigned short*)take((size_t)N * 64 * 2);
    unsigned short* P1 = (unsigned short*)take((size_t)N * 64 * 2);
    unsigned short* Q0 = (unsigned short*)take((size_t)N * 64 * 2);
    unsigned short* Q1 = (unsigned short*)take((size_t)N * 64 * 2);

    const int NB_ROW = (N + 255) / 256;
    const int NB_E = (E + 255) / 256;
    const int NB_C = N / 32;                       // 3125 blocks per graph
    const int GX_C = ((2 * NB_C + 7) / 8) * 8;     // XCD-aligned grid for conv 1-2
    const int SB = (N + 1023) / 1024;              // 98 partial blocks

    // ---- CSR build for both graphs ----
    hipMemsetAsync(zb, 0, (size_t)2 * N * 4, stream);
    k_count_dual<<<dim3(NB_E, 2), 256, 0, stream>>>(fei + E, sei + E, cnt0, cnt1, pos0, pos1, E);
    k_scan_partial_dual<<<dim3(SB, 2), 256, 0, stream>>>(cnt0, cnt1, part0, part1, dv0, dv1, N);
    k_scan_write_dual<<<dim3(SB, 2), 256, 0, stream>>>(cnt0, cnt1, part0, part1, rp0, rp1, N, E, SB);

    // ---- merged fill + encoders ----
    k_fillenc_dual<<<2 * NB_E + 2 * NB_ROW, 256, 0, stream>>>(
        fei, sei, pos0, pos1, rp0, rp1, col0, col1, E,
        front_x, side_x, fe_enc_w1, se_enc_w1, fe_enc_b1, se_enc_b1,
        fe_enc_w2, se_enc_w2, fe_enc_b2, se_enc_b2, dv0, dv1, Q0, Q1,
        N, NB_E, NB_ROW);

    // ---- conv layers 1-2 (XCD-partitioned dual):  Q->P->Q ----
    k_conv_dual<<<GX_C, 256, 0, stream>>>(Q0, Q1, col0, col1, rp0, rp1, dv0, dv1,
                                          fe_conv_w + 0 * 4096, se_conv_w + 0 * 4096,
                                          fe_conv_b + 0 * 64, se_conv_b + 0 * 64, P0, P1, NB_C);
    k_conv_dual<<<GX_C, 256, 0, stream>>>(P0, P1, col0, col1, rp0, rp1, dv0, dv1,
                                          fe_conv_w + 1 * 4096, se_conv_w + 1 * 4096,
                                          fe_conv_b + 1 * 64, se_conv_b + 1 * 64, Q0, Q1, NB_C);

    // ---- fused conv layer 3 + fusion-MLP + heads ----
    k_conv3_tail<<<NB_C, 256, 0, stream>>>(Q0, Q1, col0, col1, rp0, rp1, dv0, dv1,
                                           fe_conv_w + 2 * 4096, se_conv_w + 2 * 4096,
                                           fe_conv_b + 2 * 64, se_conv_b + 2 * 64,
                                           fus_w1, fus_b1, fus_w2, fus_b2,
                                           out_w, out_b, cls_w, cls_b, (float*)d_out, N);
}

// Round 14
// 693.086 us; speedup vs baseline: 1.1307x; 1.1307x over previous
//
#include <hip/hip_runtime.h>

#define DEV __device__ __forceinline__

static const int NN = 100000;
static const int EE = 1000000;
static const int ECAP = 1024;   // LDS-staged edges per block (32 nodes, avg ~320)

typedef unsigned int uv4 __attribute__((ext_vector_type(4)));

DEV float bf2f(unsigned int h) {
    unsigned int u = h << 16;
    float f;
    __builtin_memcpy(&f, &u, 4);
    return f;
}
DEV unsigned short f2bf(float f) {  // round-to-nearest-even
    unsigned int u;
    __builtin_memcpy(&u, &f, 4);
    u = u + 0x7FFFu + ((u >> 16) & 1u);
    return (unsigned short)(u >> 16);
}
DEV unsigned int pk2(float a, float b) {
    return (unsigned int)f2bf(a) | ((unsigned int)f2bf(b) << 16);
}
DEV void unpack8(uint4 u, float* v) {
    v[0] = bf2f(u.x & 0xffffu); v[1] = bf2f(u.x >> 16);
    v[2] = bf2f(u.y & 0xffffu); v[3] = bf2f(u.y >> 16);
    v[4] = bf2f(u.z & 0xffffu); v[5] = bf2f(u.z >> 16);
    v[6] = bf2f(u.w & 0xffffu); v[7] = bf2f(u.w >> 16);
}

// ---------------- CSR build (dual-graph via blockIdx.y) ----------------
__global__ __launch_bounds__(256) void k_count_dual(const int* __restrict__ d0, const int* __restrict__ d1,
                                                    int* __restrict__ c0, int* __restrict__ c1,
                                                    int* __restrict__ p0, int* __restrict__ p1, int e) {
    int g = blockIdx.y;
    const int* dst = g ? d1 : d0;
    int* cnt = g ? c1 : c0;
    int* pos = g ? p1 : p0;
    int i = blockIdx.x * blockDim.x + threadIdx.x;
    if (i < e) pos[i] = atomicAdd(&cnt[dst[i]], 1);
}
__global__ __launch_bounds__(256) void k_scan_partial_dual(const int* __restrict__ c0, const int* __restrict__ c1,
                                                           int* __restrict__ p0, int* __restrict__ p1,
                                                           float* __restrict__ v0, float* __restrict__ v1, int n) {
    int g = blockIdx.y;
    const int* cnt = g ? c1 : c0;
    int* partial = g ? p1 : p0;
    float* dinv = g ? v1 : v0;
    __shared__ int lds[256];
    int base = blockIdx.x * 1024;
    int t = threadIdx.x;
    int s = 0;
#pragma unroll
    for (int i = 0; i < 4; i++) {
        int idx = base + t * 4 + i;
        int c = (idx < n) ? cnt[idx] : 0;
        if (idx < n) dinv[idx] = rsqrtf((float)c + 1.0f);
        s += c;
    }
    lds[t] = s;
    __syncthreads();
    for (int off = 128; off > 0; off >>= 1) {
        if (t < off) lds[t] += lds[t + off];
        __syncthreads();
    }
    if (t == 0) partial[blockIdx.x] = lds[0];
}
// scan_write with INLINE top-level scan of partials (scan_single eliminated)
__global__ __launch_bounds__(256) void k_scan_write_dual(const int* __restrict__ c0, const int* __restrict__ c1,
                                                         const int* __restrict__ p0, const int* __restrict__ p1,
                                                         int* __restrict__ r0, int* __restrict__ r1,
                                                         int n, int total, int B) {
    int g = blockIdx.y;
    const int* cnt = g ? c1 : c0;
    const int* partial = g ? p1 : p0;
    int* rowptr = g ? r1 : r0;
    __shared__ int val[256];
    __shared__ int top[256];
    __shared__ int lds[256];
    __shared__ int base_s;
    int t = threadIdx.x;
    int pv = (t < B) ? partial[t] : 0;
    val[t] = pv;
    top[t] = pv;
    __syncthreads();
    for (int off = 1; off < 256; off <<= 1) {
        int x = (t >= off) ? top[t - off] : 0;
        __syncthreads();
        top[t] += x;
        __syncthreads();
    }
    if (t == 0) base_s = top[blockIdx.x] - val[blockIdx.x];
    __syncthreads();
    int base = blockIdx.x * 1024;
    int v[4];
    int s = 0;
#pragma unroll
    for (int i = 0; i < 4; i++) {
        int idx = base + t * 4 + i;
        v[i] = (idx < n) ? cnt[idx] : 0;
        s += v[i];
    }
    lds[t] = s;
    __syncthreads();
    int mine = s;
    for (int off = 1; off < 256; off <<= 1) {
        int x = (t >= off) ? lds[t - off] : 0;
        __syncthreads();
        lds[t] += x;
        __syncthreads();
    }
    int run = lds[t] - mine + base_s;
#pragma unroll
    for (int i = 0; i < 4; i++) {
        int idx = base + t * 4 + i;
        if (idx < n) rowptr[idx] = run;
        run += v[i];
    }
    if (blockIdx.x == 0 && t == 0) rowptr[n] = total;
}

// ---------------- merged fill + encoder (independent work, one dispatch) ----------------
__global__ __launch_bounds__(256, 4) void k_fillenc_dual(
    const int* __restrict__ s0, const int* __restrict__ s1,
    const int* __restrict__ q0, const int* __restrict__ q1,
    const int* __restrict__ r0, const int* __restrict__ r1,
    int* __restrict__ col0, int* __restrict__ col1, int e,
    const float* __restrict__ x0, const float* __restrict__ x1,
    const float* __restrict__ w1a, const float* __restrict__ w1b,
    const float* __restrict__ b1a, const float* __restrict__ b1b,
    const float* __restrict__ w2a, const float* __restrict__ w2b,
    const float* __restrict__ b2a, const float* __restrict__ b2b,
    const float* __restrict__ v0, const float* __restrict__ v1,
    unsigned short* __restrict__ y0, unsigned short* __restrict__ y1,
    int n, int nbe, int nbr) {
    int bx = blockIdx.x;
    int t = threadIdx.x;
    if (bx < 2 * nbe) {
        // ---- fill path ----
        int g = (bx >= nbe) ? 1 : 0;
        const int* src = g ? s1 : s0;
        const int* dstv = src + e;
        const int* pos = g ? q1 : q0;
        const int* rowptr = g ? r1 : r0;
        int* col = g ? col1 : col0;
        int i = (bx - g * nbe) * 256 + t;
        if (i >= e) return;
        int s = src[i], d = dstv[i];
        col[rowptr[d] + pos[i]] = s;
        return;
    }
    // ---- enc path (register-bounded) ----
    int bx2 = bx - 2 * nbe;
    int g = (bx2 >= nbr) ? 1 : 0;
    const float* x = g ? x1 : x0;
    const float* w1 = g ? w1b : w1a;
    const float* b1 = g ? b1b : b1a;
    const float* w2 = g ? w2b : w2a;
    const float* b2 = g ? b2b : b2a;
    const float* dinv = g ? v1 : v0;
    unsigned short* out = g ? y1 : y0;
    int r = (bx2 - g * nbr) * 256 + t;
    if (r >= n) return;
    float4 xv = reinterpret_cast<const float4*>(x)[r];
    float xk[4] = {xv.x, xv.y, xv.z, xv.w};
    float d = dinv[r];
    uint4* o = reinterpret_cast<uint4*>(out + (size_t)r * 64);
#pragma unroll 1
    for (int oc = 0; oc < 4; oc++) {
        float h2[16];
#pragma unroll
        for (int j = 0; j < 16; j++) h2[j] = b2[oc * 16 + j];
#pragma unroll 1
        for (int c = 0; c < 8; c++) {
            float h[8];
#pragma unroll
            for (int i = 0; i < 8; i++) h[i] = b1[c * 8 + i];
#pragma unroll
            for (int k = 0; k < 4; k++) {
#pragma unroll
                for (int i = 0; i < 8; i++) h[i] = fmaf(xk[k], w1[k * 64 + c * 8 + i], h[i]);
            }
#pragma unroll
            for (int i = 0; i < 8; i++) h[i] = fmaxf(h[i], 0.0f);
#pragma unroll
            for (int i = 0; i < 8; i++) {
                const float* wr = w2 + (c * 8 + i) * 64 + oc * 16;
#pragma unroll
                for (int j = 0; j < 16; j++) h2[j] = fmaf(h[i], wr[j], h2[j]);
            }
        }
        uint4 u0, u1;
        u0.x = pk2(h2[0] * d, h2[1] * d);   u0.y = pk2(h2[2] * d, h2[3] * d);
        u0.z = pk2(h2[4] * d, h2[5] * d);   u0.w = pk2(h2[6] * d, h2[7] * d);
        u1.x = pk2(h2[8] * d, h2[9] * d);   u1.y = pk2(h2[10] * d, h2[11] * d);
        u1.z = pk2(h2[12] * d, h2[13] * d); u1.w = pk2(h2[14] * d, h2[15] * d);
        o[oc * 2 + 0] = u0;
        o[oc * 2 + 1] = u1;
    }
}

// ---------------- fused GCN layer (pre-scaled input h' = h*dinv) ----------------
// z[d] = dinv[d] * (sum_{s in N(d)} h'[s] + h'[d]);  y = relu(z W + b);
// store y*dinv (scale_store=1, feeds next conv) or y (scale_store=0, final layer).
DEV void add_edge_v(float* acc, uint4 u) {
    float v[8];
    unpack8(u, v);
#pragma unroll
    for (int i = 0; i < 8; i++) acc[i] += v[i];
}
__global__ __launch_bounds__(256) void k_conv_dual(const unsigned short* __restrict__ x0,
                                                   const unsigned short* __restrict__ x1,
                                                   const int* __restrict__ col0, const int* __restrict__ col1,
                                                   const int* __restrict__ r0, const int* __restrict__ r1,
                                                   const float* __restrict__ v0, const float* __restrict__ v1,
                                                   const float* __restrict__ w0, const float* __restrict__ w1,
                                                   const float* __restrict__ b0, const float* __restrict__ b1,
                                                   unsigned short* __restrict__ y0, unsigned short* __restrict__ y1,
                                                   int nblk, int scale_store) {
    int bx = blockIdx.x;
    int xcd = bx & 7;
    int g = xcd >> 2;                    // 0..3 -> graph0, 4..7 -> graph1
    int lin = (bx >> 3) * 4 + (xcd & 3); // per-graph block index
    if (lin >= nblk) return;             // block-uniform exit (barriers safe)
    const unsigned short* x = g ? x1 : x0;
    const int* col = g ? col1 : col0;
    const int* rowptr = g ? r1 : r0;
    const float* dinv = g ? v1 : v0;
    const float* w = g ? w1 : w0;
    const float* b = g ? b1 : b0;
    unsigned short* y = g ? y1 : y0;

    __shared__ int eds[ECAP];        // 4 KB staged src indices
    __shared__ float agg[32][68];    // pad 64->68: phase-2 reads conflict-free

    int t = threadIdx.x;
    int cl = t >> 3;   // local node 0..31
    int ln = t & 7;    // feature-octet lane
    int node = lin * 32 + cl;
    int fbase = ln * 8;

    int nbase = lin * 32;
    int ebase = rowptr[nbase];
    int L = rowptr[nbase + 32] - ebase;
    int Ls = (L < ECAP) ? L : ECAP;
    for (int i = t; i < Ls; i += 256) {
        eds[i] = __builtin_nontemporal_load(col + ebase + i);
    }

    float acc[8];
    float d = dinv[node];
    {
        uint4 su = *reinterpret_cast<const uint4*>(x + (size_t)node * 64 + fbase);
        float sv[8];
        unpack8(su, sv);
#pragma unroll
        for (int i = 0; i < 8; i++) acc[i] = sv[i];   // self term h'[d]
    }
    int e = rowptr[node] - ebase, e1 = rowptr[node + 1] - ebase;
    __syncthreads();

    if (e1 <= ECAP) {
        // 8 independent gathers per epoch (deg~10 -> ~2 epochs)
        for (; e + 8 <= e1; e += 8) {
            int s0 = eds[e + 0], s1 = eds[e + 1], s2 = eds[e + 2], s3 = eds[e + 3];
            int s4 = eds[e + 4], s5 = eds[e + 5], s6 = eds[e + 6], s7 = eds[e + 7];
            uint4 u0 = *reinterpret_cast<const uint4*>(x + (size_t)s0 * 64 + fbase);
            uint4 u1 = *reinterpret_cast<const uint4*>(x + (size_t)s1 * 64 + fbase);
            uint4 u2 = *reinterpret_cast<const uint4*>(x + (size_t)s2 * 64 + fbase);
            uint4 u3 = *reinterpret_cast<const uint4*>(x + (size_t)s3 * 64 + fbase);
            uint4 u4 = *reinterpret_cast<const uint4*>(x + (size_t)s4 * 64 + fbase);
            uint4 u5 = *reinterpret_cast<const uint4*>(x + (size_t)s5 * 64 + fbase);
            uint4 u6 = *reinterpret_cast<const uint4*>(x + (size_t)s6 * 64 + fbase);
            uint4 u7 = *reinterpret_cast<const uint4*>(x + (size_t)s7 * 64 + fbase);
            add_edge_v(acc, u0); add_edge_v(acc, u1); add_edge_v(acc, u2); add_edge_v(acc, u3);
            add_edge_v(acc, u4); add_edge_v(acc, u5); add_edge_v(acc, u6); add_edge_v(acc, u7);
        }
        if (e + 4 <= e1) {
            int s0 = eds[e + 0], s1 = eds[e + 1], s2 = eds[e + 2], s3 = eds[e + 3];
            uint4 u0 = *reinterpret_cast<const uint4*>(x + (size_t)s0 * 64 + fbase);
            uint4 u1 = *reinterpret_cast<const uint4*>(x + (size_t)s1 * 64 + fbase);
            uint4 u2 = *reinterpret_cast<const uint4*>(x + (size_t)s2 * 64 + fbase);
            uint4 u3 = *reinterpret_cast<const uint4*>(x + (size_t)s3 * 64 + fbase);
            add_edge_v(acc, u0); add_edge_v(acc, u1); add_edge_v(acc, u2); add_edge_v(acc, u3);
            e += 4;
        }
        if (e + 2 <= e1) {
            int s0 = eds[e + 0], s1 = eds[e + 1];
            uint4 u0 = *reinterpret_cast<const uint4*>(x + (size_t)s0 * 64 + fbase);
            uint4 u1 = *reinterpret_cast<const uint4*>(x + (size_t)s1 * 64 + fbase);
            add_edge_v(acc, u0); add_edge_v(acc, u1);
            e += 2;
        }
        if (e < e1) {
            int s0 = eds[e];
            uint4 u0 = *reinterpret_cast<const uint4*>(x + (size_t)s0 * 64 + fbase);
            add_edge_v(acc, u0);
        }
    } else {
        // overflow fallback (essentially never)
        for (; e < e1; e++) {
            int s0 = __builtin_nontemporal_load(col + ebase + e);
            uint4 u0 = *reinterpret_cast<const uint4*>(x + (size_t)s0 * 64 + fbase);
            add_edge_v(acc, u0);
        }
    }
    // z = dinv[d] * acc
#pragma unroll
    for (int i = 0; i < 8; i += 4) {
        *reinterpret_cast<float4*>(&agg[cl][fbase + i]) =
            make_float4(acc[i] * d, acc[i + 1] * d, acc[i + 2] * d, acc[i + 3] * d);
    }
    __syncthreads();

    // phase 2: out[fbase..fbase+8) = b + sum_k agg[cl][k] * W[k][fbase..]
    float out[8];
#pragma unroll
    for (int i = 0; i < 8; i++) out[i] = b[fbase + i];
#pragma unroll 4
    for (int k4 = 0; k4 < 16; k4++) {
        float4 av = *reinterpret_cast<const float4*>(&agg[cl][k4 * 4]);
        float a[4] = {av.x, av.y, av.z, av.w};
#pragma unroll
        for (int kk = 0; kk < 4; kk++) {
            const float4* wr = reinterpret_cast<const float4*>(w + (k4 * 4 + kk) * 64 + fbase);
            float4 wv0 = wr[0], wv1 = wr[1];
            out[0] = fmaf(a[kk], wv0.x, out[0]);
            out[1] = fmaf(a[kk], wv0.y, out[1]);
            out[2] = fmaf(a[kk], wv0.z, out[2]);
            out[3] = fmaf(a[kk], wv0.w, out[3]);
            out[4] = fmaf(a[kk], wv1.x, out[4]);
            out[5] = fmaf(a[kk], wv1.y, out[5]);
            out[6] = fmaf(a[kk], wv1.z, out[6]);
            out[7] = fmaf(a[kk], wv1.w, out[7]);
        }
    }
    float sc = scale_store ? d : 1.0f;
    uint4 ou;
    float r[8];
#pragma unroll
    for (int i = 0; i < 8; i++) r[i] = fmaxf(out[i], 0.0f) * sc;
    ou.x = pk2(r[0], r[1]); ou.y = pk2(r[2], r[3]); ou.z = pk2(r[4], r[5]); ou.w = pk2(r[6], r[7]);
    *reinterpret_cast<uint4*>(y + (size_t)node * 64 + fbase) = ou;
}

// ---------------- fused tail: concat-MLP + both heads ----------------
__global__ __launch_bounds__(256) void k_tail(const unsigned short* __restrict__ F,
                                              const unsigned short* __restrict__ S,
                                              const float* __restrict__ w1, const float* __restrict__ b1,
                                              const float* __restrict__ w2, const float* __restrict__ b2,
                                              const float* __restrict__ ow, const float* __restrict__ ob,
                                              const float* __restrict__ cw, const float* __restrict__ cb,
                                              float* __restrict__ out, int n) {
    int r = blockIdx.x * blockDim.x + threadIdx.x;
    if (r >= n) return;
    float h1[64];
#pragma unroll
    for (int j = 0; j < 64; j++) h1[j] = b1[j];
    const uint4* Fr = reinterpret_cast<const uint4*>(F + (size_t)r * 64);
    const uint4* Sr = reinterpret_cast<const uint4*>(S + (size_t)r * 64);
#pragma unroll 1
    for (int k0 = 0; k0 < 8; k0++) {
        uint4 u = Fr[k0];
        float v[8];
        unpack8(u, v);
        const float* wk = w1 + k0 * 8 * 64;
#pragma unroll
        for (int i = 0; i < 8; i++) {
#pragma unroll
            for (int j = 0; j < 64; j++) h1[j] = fmaf(v[i], wk[i * 64 + j], h1[j]);
        }
    }
#pragma unroll 1
    for (int k0 = 0; k0 < 8; k0++) {
        uint4 u = Sr[k0];
        float v[8];
        unpack8(u, v);
        const float* wk = w1 + (64 + k0 * 8) * 64;
#pragma unroll
        for (int i = 0; i < 8; i++) {
#pragma unroll
            for (int j = 0; j < 64; j++) h1[j] = fmaf(v[i], wk[i * 64 + j], h1[j]);
        }
    }
#pragma unroll
    for (int j = 0; j < 64; j++) h1[j] = fmaxf(h1[j], 0.0f);

    float nf[32];
#pragma unroll
    for (int j = 0; j < 32; j++) nf[j] = ob[j];
    float nt0 = cb[0], nt1 = cb[1];
#pragma unroll 1
    for (int c = 0; c < 8; c++) {  // h2 in chunks of 8
        float h2[8];
#pragma unroll
        for (int i = 0; i < 8; i++) h2[i] = b2[c * 8 + i];
#pragma unroll
        for (int k = 0; k < 64; k++) {
            const float* wr = w2 + k * 64 + c * 8;
#pragma unroll
            for (int i = 0; i < 8; i++) h2[i] = fmaf(h1[k], wr[i], h2[i]);
        }
#pragma unroll
        for (int i = 0; i < 8; i++) {
            int kk = c * 8 + i;
#pragma unroll
            for (int j = 0; j < 32; j++) nf[j] = fmaf(h2[i], ow[kk * 32 + j], nf[j]);
            nt0 = fmaf(h2[i], cw[kk * 2 + 0], nt0);
            nt1 = fmaf(h2[i], cw[kk * 2 + 1], nt1);
        }
    }
    float4* o = reinterpret_cast<float4*>(out + (size_t)r * 32);
#pragma unroll
    for (int c = 0; c < 8; c++) {
        o[c] = make_float4(nf[c * 4 + 0], nf[c * 4 + 1], nf[c * 4 + 2], nf[c * 4 + 3]);
    }
    float2* o2 = reinterpret_cast<float2*>(out + (size_t)NN * 32);
    o2[r] = make_float2(nt0, nt1);
}

extern "C" void kernel_launch(void* const* d_in, const int* in_sizes, int n_in,
                              void* d_out, int out_size, void* d_ws, size_t ws_size,
                              hipStream_t stream) {
    const int N = NN, E = EE;
    const float* front_x = (const float*)d_in[0];
    const float* side_x = (const float*)d_in[1];
    const int* fei = (const int*)d_in[2];
    const int* sei = (const int*)d_in[3];
    const float* fe_enc_w1 = (const float*)d_in[4];
    const float* fe_enc_b1 = (const float*)d_in[5];
    const float* fe_enc_w2 = (const float*)d_in[6];
    const float* fe_enc_b2 = (const float*)d_in[7];
    const float* fe_conv_w = (const float*)d_in[8];
    const float* fe_conv_b = (const float*)d_in[9];
    const float* se_enc_w1 = (const float*)d_in[10];
    const float* se_enc_b1 = (const float*)d_in[11];
    const float* se_enc_w2 = (const float*)d_in[12];
    const float* se_enc_b2 = (const float*)d_in[13];
    const float* se_conv_w = (const float*)d_in[14];
    const float* se_conv_b = (const float*)d_in[15];
    const float* fus_w1 = (const float*)d_in[16];
    const float* fus_b1 = (const float*)d_in[17];
    const float* fus_w2 = (const float*)d_in[18];
    const float* fus_b2 = (const float*)d_in[19];
    const float* out_w = (const float*)d_in[20];
    const float* out_b = (const float*)d_in[21];
    const float* cls_w = (const float*)d_in[22];
    const float* cls_b = (const float*)d_in[23];

    // workspace carve (256B aligned)
    char* ws = (char*)d_ws;
    size_t off = 0;
    auto take = [&](size_t bytes) -> char* {
        char* p = ws + off;
        off = (off + bytes + 255) & ~(size_t)255;
        return p;
    };
    int* zb = (int*)take((size_t)2 * N * 4);  // cnt0,cnt1 (zeroed)
    int* cnt0 = zb;
    int* cnt1 = zb + N;
    int* pos0 = (int*)take((size_t)E * 4);
    int* pos1 = (int*)take((size_t)E * 4);
    int* rp0 = (int*)take((size_t)(N + 1) * 4);
    int* rp1 = (int*)take((size_t)(N + 1) * 4);
    float* dv0 = (float*)take((size_t)N * 4);
    float* dv1 = (float*)take((size_t)N * 4);
    int* part0 = (int*)take(256 * 4);
    int* part1 = (int*)take(256 * 4);
    int* col0 = (int*)take((size_t)E * 4);
    int* col1 = (int*)take((size_t)E * 4);
    unsigned short* P0 = (unsigned short*)take((size_t)N * 64 * 2);
    unsigned short* P1 = (unsigned short*)take((size_t)N * 64 * 2);
    unsigned short* Q0 = (unsigned short*)take((size_t)N * 64 * 2);
    unsigned short* Q1 = (unsigned short*)take((size_t)N * 64 * 2);

    const int NB_ROW = (N + 255) / 256;
    const int NB_E = (E + 255) / 256;
    const int NB_C = N / 32;                       // 3125 blocks per graph
    const int GX_C = ((2 * NB_C + 7) / 8) * 8;     // XCD-aligned grid for conv
    const int SB = (N + 1023) / 1024;              // 98 partial blocks

    // ---- CSR build for both graphs ----
    hipMemsetAsync(zb, 0, (size_t)2 * N * 4, stream);
    k_count_dual<<<dim3(NB_E, 2), 256, 0, stream>>>(fei + E, sei + E, cnt0, cnt1, pos0, pos1, E);
    k_scan_partial_dual<<<dim3(SB, 2), 256, 0, stream>>>(cnt0, cnt1, part0, part1, dv0, dv1, N);
    k_scan_write_dual<<<dim3(SB, 2), 256, 0, stream>>>(cnt0, cnt1, part0, part1, rp0, rp1, N, E, SB);

    // ---- merged fill + encoders (one dispatch; independent work) ----
    k_fillenc_dual<<<2 * NB_E + 2 * NB_ROW, 256, 0, stream>>>(
        fei, sei, pos0, pos1, rp0, rp1, col0, col1, E,
        front_x, side_x, fe_enc_w1, se_enc_w1, fe_enc_b1, se_enc_b1,
        fe_enc_w2, se_enc_w2, fe_enc_b2, se_enc_b2, dv0, dv1, Q0, Q1,
        N, NB_E, NB_ROW);

    // ---- 3 fused conv layers (XCD-partitioned dual, LDS-staged col):  Q->P->Q->P ----
    k_conv_dual<<<GX_C, 256, 0, stream>>>(Q0, Q1, col0, col1, rp0, rp1, dv0, dv1,
                                          fe_conv_w + 0 * 4096, se_conv_w + 0 * 4096,
                                          fe_conv_b + 0 * 64, se_conv_b + 0 * 64, P0, P1, NB_C, 1);
    k_conv_dual<<<GX_C, 256, 0, stream>>>(P0, P1, col0, col1, rp0, rp1, dv0, dv1,
                                          fe_conv_w + 1 * 4096, se_conv_w + 1 * 4096,
                                          fe_conv_b + 1 * 64, se_conv_b + 1 * 64, Q0, Q1, NB_C, 1);
    k_conv_dual<<<GX_C, 256, 0, stream>>>(Q0, Q1, col0, col1, rp0, rp1, dv0, dv1,
                                          fe_conv_w + 2 * 4096, se_conv_w + 2 * 4096,
                                          fe_conv_b + 2 * 64, se_conv_b + 2 * 64, P0, P1, NB_C, 0);

    // ---- fused fusion-MLP + heads ----
    k_tail<<<NB_ROW, 256, 0, stream>>>(P0, P1, fus_w1, fus_b1, fus_w2, fus_b2,
                                       out_w, out_b, cls_w, cls_b, (float*)d_out, N);
}